// Round 3
// 373.091 us; speedup vs baseline: 1.1285x; 1.1285x over previous
//
#include <hip/hip_runtime.h>

#define NN 30000
#define NE 480000
#define NG 512
#define MAXD 48
#define BATCH 32
#define NB 938    // ceil(30000/32)
#define HPAD 144  // h_s row stride in shorts
#define NGB 469   // ceil(30000/64) for the 64-row GEMM kernels

typedef __attribute__((ext_vector_type(8))) short short8;
typedef __attribute__((ext_vector_type(4))) short s16x4;
typedef __attribute__((ext_vector_type(4))) float f32x4;

static __device__ __forceinline__ short f2bs(float f) {
  unsigned u = __builtin_bit_cast(unsigned, f);
  u = (u + 0x7fffu + ((u >> 16) & 1u)) >> 16;
  return (short)u;
}
static __device__ __forceinline__ float bs2f(short s) {
  unsigned u = ((unsigned)(unsigned short)s) << 16;
  return __builtin_bit_cast(float, u);
}
static __device__ __forceinline__ float sigf(float x) {
  return __builtin_amdgcn_rcpf(1.0f + __expf(-x));
}
static __device__ __forceinline__ float tanh_(float x) {
  return 1.0f - 2.0f * __builtin_amdgcn_rcpf(1.0f + __expf(2.0f * x));
}
// async 16B-per-lane gather into LDS: dest = ldsbase + lane*16
static __device__ __forceinline__ void gl_lds16(const short* g, short* l) {
  __builtin_amdgcn_global_load_lds(
      (const __attribute__((address_space(1))) void*)g,
      (__attribute__((address_space(3))) void*)l, 16, 0, 0);
}

// Pin a bf16x8 MFMA B-fragment to AGPRs. gfx950's unified RF lets MFMA read
// A/B operands from AGPR (cdna4_isa.md §10: AV-class sources on gfx90a+), so
// the builtin consumes the pinned value with no accvgpr_read copies. This
// moves the 128 loop-invariant W registers out of the arch-VGPR file, which
// round-0 rocprof showed was spilling ~105 MB/dispatch (WRITE_SIZE 108 MB vs
// 7.7 MB of real writes at VGPR_Count=128 arch). NOTE: round 1 tried a full
// inline-asm MFMA with an "a" constraint — correctness failed (absmax 0.47)
// because inline asm is opaque to the MFMA hazard recognizer (missing s_nops
// before VALU reads of vdst). The empty-asm pin keeps the builtin's
// compiler-managed hazards. (Round 2 of this source never ran: container
// acquisition failed twice — infra, not kernel.)
#define PIN_AGPR(w_) asm("" : "+a"(w_))

// ---- prep: segment starts/ends via boundary detection (src sorted; no atomics)
__global__ void k_edges(const int* __restrict__ src, int* __restrict__ starts,
                        int* __restrict__ ends) {
  int e = blockIdx.x * 256 + threadIdx.x;
  if (e >= NE) return;
  int s = src[e];
  if (e == 0 || src[e - 1] != s) starts[s] = e;
  if (e == NE - 1 || src[e + 1] != s) ends[s] = e + 1;
}

// ---- degree histogram + descending-degree bucket offsets (one block) ----
__global__ void k_hs(const int* __restrict__ starts, const int* __restrict__ ends,
                     int* __restrict__ offs) {
  __shared__ int hist[MAXD + 1];
  int tid = threadIdx.x;
  if (tid <= MAXD) hist[tid] = 0;
  __syncthreads();
  for (int n = tid; n < NN; n += 1024) {
    int c = ends[n] - starts[n]; c = c > MAXD ? MAXD : c;
    atomicAdd(&hist[c], 1);
  }
  __syncthreads();
  if (tid == 0) {
    int total = 0;
    for (int b = MAXD; b >= 0; --b) { offs[b] = total; total += hist[b]; }
  }
}

__global__ void k_scatter(const int* __restrict__ starts, const int* __restrict__ ends,
                          int* __restrict__ offs, int* __restrict__ order) {
  int n = blockIdx.x * 256 + threadIdx.x;
  if (n >= NN) return;
  int c = ends[n] - starts[n]; c = c > MAXD ? MAXD : c;
  int slot = atomicAdd(&offs[c], 1);
  order[slot] = n;  // descending-degree permutation
}

__global__ void k_nbr(const int* __restrict__ src, const int* __restrict__ trg,
                      const int* __restrict__ starts, int* __restrict__ nbr) {
  int e = blockIdx.x * 256 + threadIdx.x;
  if (e >= NE) return;
  int s = src[e];
  int pos = e - starts[s];
  if (pos < MAXD) nbr[s * MAXD + pos] = trg[e];
}

// ---- proj = X @ W_ih.T + (b_ih+b_hh), bf16 MFMA, permuted layout:
// j = g*128 + wv*32 + db*16 + lc  ->  pos = (wv*16+lc)*8 + g*2 + db  ----
__global__ __launch_bounds__(256)
__attribute__((amdgpu_waves_per_eu(2, 2))) void k_proj(
    const float* __restrict__ x, const float* __restrict__ W_ih,
    const float* __restrict__ b_ih, const float* __restrict__ b_hh,
    short* __restrict__ proj) {
  __shared__ __align__(16) short xs[64 * HPAD];
  const int tid = threadIdx.x;
  const int wv = tid >> 6, lane = tid & 63, lq = lane >> 4, lc = lane & 15;
  const int base = blockIdx.x * 64;

  for (int idx4 = tid; idx4 < 64 * 32; idx4 += 256) {
    int row = idx4 >> 5, k4 = (idx4 & 31) << 2;
    f32x4 v = (f32x4){0.f, 0.f, 0.f, 0.f};
    if (base + row < NN) v = *(const f32x4*)&x[(base + row) * 128 + k4];
    s16x4 p; p[0] = f2bs(v[0]); p[1] = f2bs(v[1]); p[2] = f2bs(v[2]); p[3] = f2bs(v[3]);
    *(s16x4*)&xs[row * HPAD + k4] = p;
  }
  short8 wfrag[4][2][4];
#pragma unroll
  for (int g = 0; g < 4; ++g)
#pragma unroll
    for (int db = 0; db < 2; ++db)
#pragma unroll
      for (int kt = 0; kt < 4; ++kt) {
        const float* p =
            &W_ih[(g * 128 + wv * 32 + db * 16 + lc) * 128 + kt * 32 + lq * 8];
        f32x4 a = *(const f32x4*)p;
        f32x4 b = *(const f32x4*)(p + 4);
        short8 w;
        w[0] = f2bs(a[0]); w[1] = f2bs(a[1]); w[2] = f2bs(a[2]); w[3] = f2bs(a[3]);
        w[4] = f2bs(b[0]); w[5] = f2bs(b[1]); w[6] = f2bs(b[2]); w[7] = f2bs(b[3]);
        PIN_AGPR(w);
        wfrag[g][db][kt] = w;
      }
  float bias_v[4][2];
#pragma unroll
  for (int g = 0; g < 4; ++g)
#pragma unroll
    for (int db = 0; db < 2; ++db) {
      int j = g * 128 + wv * 32 + db * 16 + lc;
      bias_v[g][db] = b_ih[j] + b_hh[j];
    }
  __syncthreads();

#pragma unroll
  for (int mt = 0; mt < 4; ++mt) {
    short8 afrag[4];
#pragma unroll
    for (int kt = 0; kt < 4; ++kt)
      afrag[kt] = *(const short8*)&xs[(mt * 16 + lc) * HPAD + kt * 32 + lq * 8];
    f32x4 acc[4][2];
#pragma unroll
    for (int g = 0; g < 4; ++g)
#pragma unroll
      for (int db = 0; db < 2; ++db) {
        float b = bias_v[g][db];
        acc[g][db] = (f32x4){b, b, b, b};
#pragma unroll
        for (int kt = 0; kt < 4; ++kt)
          acc[g][db] = __builtin_amdgcn_mfma_f32_16x16x32_bf16(
              afrag[kt], wfrag[g][db][kt], acc[g][db], 0, 0, 0);
      }
#pragma unroll
    for (int r = 0; r < 4; ++r) {
      int row = base + mt * 16 + lq * 4 + r;
      if (row < NN) {
        short8 w;
        w[0] = f2bs(acc[0][0][r]); w[1] = f2bs(acc[0][1][r]);
        w[2] = f2bs(acc[1][0][r]); w[3] = f2bs(acc[1][1][r]);
        w[4] = f2bs(acc[2][0][r]); w[5] = f2bs(acc[2][1][r]);
        w[6] = f2bs(acc[3][0][r]); w[7] = f2bs(acc[3][1][r]);
        *(short8*)&proj[row * NG + (wv * 16 + lc) * 8] = w;
      }
    }
  }
}

// ---- LSTM: W_hh B-frags AGPR-pinned (see PIN_AGPR); distance-1 prefetch of
// the proj gather via global_load_lds into a wave-private LDS buffer;
// double-buffered h_s with register copy-forward -> one barrier per step.
// waves_per_eu(2,2): 256-reg total budget = 128 AGPR (wfrag) + arch rest. ----
__global__ __launch_bounds__(256)
__attribute__((amdgpu_waves_per_eu(2, 2))) void k_lstm(
    const float* __restrict__ W_hh, const short* __restrict__ proj,
    const int* __restrict__ order, const int* __restrict__ starts,
    const int* __restrict__ ends, const int* __restrict__ nbr,
    short* __restrict__ agg) {
  __shared__ __align__(16) short h_s[2][BATCH * HPAD];   // 18432 B
  __shared__ __align__(16) short pbuf[4][8][64 * 8];     // 32768 B, wave-private slots
  __shared__ unsigned short nbr_s[BATCH][MAXD];          // 3072 B
  __shared__ int nodes_s[BATCH];
  __shared__ int cnts_s[BATCH];

  const int tid = threadIdx.x;
  const int wv = tid >> 6, lane = tid & 63, lq = lane >> 4, lc = lane & 15;

  short8 wfrag[4][2][4];
#pragma unroll
  for (int g = 0; g < 4; ++g)
#pragma unroll
    for (int db = 0; db < 2; ++db)
#pragma unroll
      for (int kt = 0; kt < 4; ++kt) {
        const float* p =
            &W_hh[(g * 128 + wv * 32 + db * 16 + lc) * 128 + kt * 32 + lq * 8];
        f32x4 a = *(const f32x4*)p;
        f32x4 b = *(const f32x4*)(p + 4);
        short8 w;
        w[0] = f2bs(a[0]); w[1] = f2bs(a[1]); w[2] = f2bs(a[2]); w[3] = f2bs(a[3]);
        w[4] = f2bs(b[0]); w[5] = f2bs(b[1]); w[6] = f2bs(b[2]); w[7] = f2bs(b[3]);
        PIN_AGPR(w);
        wfrag[g][db][kt] = w;
      }

  const int batch = blockIdx.x;
  if (tid < BATCH) {
    int gidx = batch * BATCH + tid;
    int node = 0, c = 0;
    if (gidx < NN) {
      node = order[gidx];
      c = ends[node] - starts[node]; c = c > MAXD ? MAXD : c;
    }
    nodes_s[tid] = node;
    cnts_s[tid] = c;
  }
  __syncthreads();
  for (int idx = tid; idx < BATCH * HPAD / 2; idx += 256)
    ((int*)h_s[0])[idx] = 0;
  for (int idx = tid; idx < BATCH * MAXD; idx += 256) {
    int m = idx / MAXD, p = idx - m * MAXD;
    nbr_s[m][p] = (unsigned short)nbr[nodes_s[m] * MAXD + p];
  }
  __syncthreads();
  const int T = cnts_s[0];  // descending sort -> batch max

  // counts packed 4-per-int (each <= 48 fits in 8 bits)
  int cp[2];
#pragma unroll
  for (int mt = 0; mt < 2; ++mt) {
    int p = 0;
#pragma unroll
    for (int r = 0; r < 4; ++r) p |= cnts_s[mt * 16 + lq * 4 + r] << (r * 8);
    cp[mt] = p;
  }

  float c_v[2][2][4];
  s16x4 hvp[2][2];  // last-written h (bf16) for copy-forward of frozen rows
#pragma unroll
  for (int mt = 0; mt < 2; ++mt)
#pragma unroll
    for (int db = 0; db < 2; ++db) {
#pragma unroll
      for (int r = 0; r < 4; ++r) c_v[mt][db][r] = 0.0f;
      hvp[mt][db] = (s16x4){0, 0, 0, 0};
    }

  const int pcol = (wv * 16 + lc) * 8;
  if (T > 0) {  // prologue: async-gather t=0 slices into pbuf
#pragma unroll
    for (int mt = 0; mt < 2; ++mt)
#pragma unroll
      for (int r = 0; r < 4; ++r) {
        int m = mt * 16 + lq * 4 + r;
        int nb_i = (0 < ((cp[mt] >> (r * 8)) & 255)) ? (int)nbr_s[m][0] : 0;
        gl_lds16(&proj[nb_i * NG + pcol], &pbuf[wv][mt * 4 + r][0]);
      }
  }

  for (int t = 0; t < T; ++t) {
    __syncthreads();  // drains prefetch (vmcnt) + makes h writes visible
    const short* hb = h_s[t & 1];
    short* hw = h_s[(t + 1) & 1];
    const int tn = t + 1;
    const int ts = tn < MAXD ? tn : 0;
#pragma unroll
    for (int mt = 0; mt < 2; ++mt) {
      // consume this step's gathered slices (wave-private slots)
      short8 pv[4];
#pragma unroll
      for (int r = 0; r < 4; ++r)
        pv[r] = *(const short8*)&pbuf[wv][mt * 4 + r][lane * 8];
      f32x4 acc[4][2];
#pragma unroll
      for (int g = 0; g < 4; ++g)
#pragma unroll
        for (int db = 0; db < 2; ++db)
#pragma unroll
          for (int r = 0; r < 4; ++r)
            acc[g][db][r] = bs2f(pv[r][g * 2 + db]);  // x-part + bias
      __builtin_amdgcn_sched_barrier(0);  // pv fully consumed before overwrite
      if (tn < T) {  // prefetch t+1 into the same (now free) slots
#pragma unroll
        for (int r = 0; r < 4; ++r) {
          int m = mt * 16 + lq * 4 + r;
          int nb_i = (tn < ((cp[mt] >> (r * 8)) & 255)) ? (int)nbr_s[m][ts] : 0;
          gl_lds16(&proj[nb_i * NG + pcol], &pbuf[wv][mt * 4 + r][0]);
        }
      }
      __builtin_amdgcn_sched_barrier(0);  // keep prefetch issue early
      short8 afrag[4];
#pragma unroll
      for (int kt = 0; kt < 4; ++kt)
        afrag[kt] = *(const short8*)&hb[(mt * 16 + lc) * HPAD + kt * 32 + lq * 8];
#pragma unroll
      for (int g = 0; g < 4; ++g)
#pragma unroll
        for (int db = 0; db < 2; ++db)
#pragma unroll
          for (int kt = 0; kt < 4; ++kt)
            acc[g][db] = __builtin_amdgcn_mfma_f32_16x16x32_bf16(
                afrag[kt], wfrag[g][db][kt], acc[g][db], 0, 0, 0);
#pragma unroll
      for (int db = 0; db < 2; ++db)
#pragma unroll
        for (int r = 0; r < 4; ++r) {
          float iv = sigf(acc[0][db][r]);
          float fv = sigf(acc[1][db][r]);
          float gv = tanh_(acc[2][db][r]);
          float ov = sigf(acc[3][db][r]);
          float c2 = fv * c_v[mt][db][r] + iv * gv;
          float h2 = ov * tanh_(c2);
          if (t < ((cp[mt] >> (r * 8)) & 255)) {
            c_v[mt][db][r] = c2;
            hvp[mt][db][r] = f2bs(h2);
          }
        }
      // unconditional write of (new or carried) h into the other buffer
#pragma unroll
      for (int db = 0; db < 2; ++db)
#pragma unroll
        for (int r = 0; r < 4; ++r)
          hw[(mt * 16 + lq * 4 + r) * HPAD + wv * 32 + db * 16 + lc] =
              hvp[mt][db][r];
    }
  }
  __syncthreads();  // last step's h writes visible
  const short* hf = h_s[T & 1];
  for (int idx = tid; idx < BATCH * 128; idx += 256) {
    int m = idx >> 7, d = idx & 127;
    if (batch * BATCH + m < NN) agg[nodes_s[m] * 128 + d] = hf[m * HPAD + d];
  }
}

// ---- out = [x | h] @ W_out, bf16 MFMA ----
__global__ __launch_bounds__(256, 2) void k_out(
    const float* __restrict__ x, const short* __restrict__ agg,
    const float* __restrict__ Wout, float* __restrict__ out) {
  __shared__ __align__(16) short xs[64 * 272];
  const int tid = threadIdx.x;
  const int wv = tid >> 6, lane = tid & 63, lq = lane >> 4, lc = lane & 15;
  const int base = blockIdx.x * 64;

  for (int idx4 = tid; idx4 < 64 * 32; idx4 += 256) {
    int row = idx4 >> 5, k4 = (idx4 & 31) << 2;
    f32x4 v = (f32x4){0.f, 0.f, 0.f, 0.f};
    if (base + row < NN) v = *(const f32x4*)&x[(base + row) * 128 + k4];
    s16x4 p; p[0] = f2bs(v[0]); p[1] = f2bs(v[1]); p[2] = f2bs(v[2]); p[3] = f2bs(v[3]);
    *(s16x4*)&xs[row * 272 + k4] = p;
    s16x4 a = (s16x4){0, 0, 0, 0};
    if (base + row < NN) a = *(const s16x4*)&agg[(base + row) * 128 + k4];
    *(s16x4*)&xs[row * 272 + 128 + k4] = a;
  }
  short8 wf[2][8];
#pragma unroll
  for (int db = 0; db < 2; ++db)
#pragma unroll
    for (int kt = 0; kt < 8; ++kt) {
      short8 w;
#pragma unroll
      for (int jj = 0; jj < 8; ++jj)
        w[jj] = f2bs(Wout[(kt * 32 + lq * 8 + jj) * 128 + wv * 32 + db * 16 + lc]);
      wf[db][kt] = w;
    }
  __syncthreads();

#pragma unroll
  for (int mt = 0; mt < 4; ++mt) {
    short8 afrag[8];
#pragma unroll
    for (int kt = 0; kt < 8; ++kt)
      afrag[kt] = *(const short8*)&xs[(mt * 16 + lc) * 272 + kt * 32 + lq * 8];
    f32x4 acc[2];
#pragma unroll
    for (int db = 0; db < 2; ++db) {
      acc[db] = (f32x4){0.f, 0.f, 0.f, 0.f};
#pragma unroll
      for (int kt = 0; kt < 8; ++kt)
        acc[db] = __builtin_amdgcn_mfma_f32_16x16x32_bf16(
            afrag[kt], wf[db][kt], acc[db], 0, 0, 0);
    }
#pragma unroll
    for (int db = 0; db < 2; ++db)
#pragma unroll
      for (int r = 0; r < 4; ++r) {
        int row = base + mt * 16 + lq * 4 + r;
        if (row < NN)
          out[row * 128 + wv * 32 + db * 16 + lc] = acc[db][r];
      }
  }
}

extern "C" void kernel_launch(void* const* d_in, const int* in_sizes, int n_in,
                              void* d_out, int out_size, void* d_ws,
                              size_t ws_size, hipStream_t stream) {
  (void)in_sizes; (void)n_in; (void)out_size; (void)ws_size;
  const float* x     = (const float*)d_in[0];
  const float* W_ih  = (const float*)d_in[1];
  const float* W_hh  = (const float*)d_in[2];
  const float* b_ih  = (const float*)d_in[3];
  const float* b_hh  = (const float*)d_in[4];
  const float* W_out = (const float*)d_in[5];
  const int*   esrc  = (const int*)d_in[6];
  const int*   etrg  = (const int*)d_in[7];
  float* out = (float*)d_out;
  char* ws = (char*)d_ws;

  int*   starts = (int*)(ws + 0);          // 120000 B
  int*   ends   = (int*)(ws + 120064);     // 120000 B
  int*   offs   = (int*)(ws + 240128);     // 196 B
  int*   order  = (int*)(ws + 240384);     // 120000 B
  int*   nbr    = (int*)(ws + 360448);     // 5,760,000 B
  short* proj   = (short*)(ws + 6382848);  // 30,720,000 B (bf16, permuted cols)
  short* agg    = (short*)(ws + 37102848); // 7,680,000 B (bf16)

  (void)hipMemsetAsync(d_ws, 0, 240128, stream);  // starts + ends

  k_edges  <<<1875, 256, 0, stream>>>(esrc, starts, ends);
  k_hs     <<<1, 1024, 0, stream>>>(starts, ends, offs);
  k_scatter<<<118, 256, 0, stream>>>(starts, ends, offs, order);
  k_nbr    <<<1875, 256, 0, stream>>>(esrc, etrg, starts, nbr);
  k_proj   <<<NGB, 256, 0, stream>>>(x, W_ih, b_ih, b_hh, proj);
  k_lstm   <<<NB, 256, 0, stream>>>(W_hh, proj, order, starts, ends, nbr, agg);
  k_out    <<<NGB, 256, 0, stream>>>(x, agg, W_out, out);
}

// Round 4
// 260.059 us; speedup vs baseline: 1.6190x; 1.4346x over previous
//
#include <hip/hip_runtime.h>

#define NN 30000
#define NE 480000
#define NG 512
#define MAXD 48
#define BATCH 32
#define NB 938    // ceil(30000/32)
#define HPAD 144  // h_s row stride in shorts
#define NGB 469   // ceil(30000/64) for the 64-row GEMM kernels

typedef __attribute__((ext_vector_type(8))) short short8;
typedef __attribute__((ext_vector_type(4))) short s16x4;
typedef __attribute__((ext_vector_type(4))) float f32x4;

static __device__ __forceinline__ short f2bs(float f) {
  unsigned u = __builtin_bit_cast(unsigned, f);
  u = (u + 0x7fffu + ((u >> 16) & 1u)) >> 16;
  return (short)u;
}
static __device__ __forceinline__ float bs2f(short s) {
  unsigned u = ((unsigned)(unsigned short)s) << 16;
  return __builtin_bit_cast(float, u);
}
static __device__ __forceinline__ float sigf(float x) {
  return __builtin_amdgcn_rcpf(1.0f + __expf(-x));
}
static __device__ __forceinline__ float tanh_(float x) {
  return 1.0f - 2.0f * __builtin_amdgcn_rcpf(1.0f + __expf(2.0f * x));
}
// async 16B-per-lane gather into LDS: dest = ldsbase + lane*16
static __device__ __forceinline__ void gl_lds16(const short* g, short* l) {
  __builtin_amdgcn_global_load_lds(
      (const __attribute__((address_space(1))) void*)g,
      (__attribute__((address_space(3))) void*)l, 16, 0, 0);
}

// Pin a bf16x8 MFMA B-fragment to AGPRs (gfx950 unified RF: MFMA reads A/B
// from AGPR). Round-3 rocprof verified this kills the arch-VGPR spill:
// k_lstm WRITE_SIZE 107,866 KB -> 7,500 KB, dur 218 -> 180 us. Keep the
// builtin MFMA (compiler-managed hazards); round 1 showed a full inline-asm
// MFMA breaks the hazard recognizer (absmax 0.47).
#define PIN_AGPR(w_) asm("" : "+a"(w_))

// ---- prep: segment starts/ends via boundary detection (src sorted) FUSED
// with one-time weight bf16 pre-conversion into per-thread fragment layout.
// Fragment store order is [frag][tid] so consuming loads are coalesced
// (lane i reads 16B at base + i*16). Mapping must match consumers:
// wv=tid>>6, lq=(tid>>4)&3, lc=tid&15; frag f = g*8+db*4+kt (W_ih/W_hh),
// f = db*8+kt (W_out). Conversion uses the same f2bs as before -> numerics
// bit-identical to the per-block conversion it replaces. ----
#define EDGE_BLKS 1875
__global__ void k_edges_wcvt(const int* __restrict__ src, int* __restrict__ starts,
                             int* __restrict__ ends,
                             const float* __restrict__ W_ih,
                             const float* __restrict__ W_hh,
                             const float* __restrict__ Wout,
                             short* __restrict__ wih_s, short* __restrict__ whh_s,
                             short* __restrict__ wout_s) {
  const int b = blockIdx.x, tid = threadIdx.x;
  if (b < EDGE_BLKS) {
    int e = b * 256 + tid;
    if (e >= NE) return;
    int s = src[e];
    if (e == 0 || src[e - 1] != s) starts[s] = e;
    if (e == NE - 1 || src[e + 1] != s) ends[s] = e + 1;
    return;
  }
  const int f = b - EDGE_BLKS;  // 0..79
  const int wv = tid >> 6, lq = (tid >> 4) & 3, lc = tid & 15;
  if (f < 64) {
    const float* W = (f < 32) ? W_ih : W_hh;
    short* dst = (f < 32) ? wih_s : whh_s;
    const int ff = f & 31;
    const int g = ff >> 3, db = (ff >> 2) & 1, kt = ff & 3;
    const float* p = &W[(g * 128 + wv * 32 + db * 16 + lc) * 128 + kt * 32 + lq * 8];
    f32x4 a = *(const f32x4*)p;
    f32x4 c = *(const f32x4*)(p + 4);
    short8 w;
    w[0] = f2bs(a[0]); w[1] = f2bs(a[1]); w[2] = f2bs(a[2]); w[3] = f2bs(a[3]);
    w[4] = f2bs(c[0]); w[5] = f2bs(c[1]); w[6] = f2bs(c[2]); w[7] = f2bs(c[3]);
    *(short8*)&dst[(ff * 256 + tid) * 8] = w;
  } else {
    const int fo = f - 64;  // 0..15
    const int db = fo >> 3, kt = fo & 7;
    short8 w;
#pragma unroll
    for (int jj = 0; jj < 8; ++jj)
      w[jj] = f2bs(Wout[(kt * 32 + lq * 8 + jj) * 128 + wv * 32 + db * 16 + lc]);
    *(short8*)&wout_s[(fo * 256 + tid) * 8] = w;
  }
}

// ---- multi-block degree histogram (replaces single-block k_hs, which
// serialized 240 KB of reads + a serial scan on ONE CU). ghist zeroed by
// the launch-side memset. ----
__global__ void k_hist(const int* __restrict__ starts, const int* __restrict__ ends,
                       int* __restrict__ ghist) {
  __shared__ int h[MAXD + 1];
  const int tid = threadIdx.x;
  if (tid <= MAXD) h[tid] = 0;
  __syncthreads();
  int n = blockIdx.x * 256 + tid;
  if (n < NN) {
    int c = ends[n] - starts[n]; c = c > MAXD ? MAXD : c;
    atomicAdd(&h[c], 1);
  }
  __syncthreads();
  if (tid <= MAXD && h[tid] > 0) atomicAdd(&ghist[tid], h[tid]);
}

// ---- tiny descending-bucket exclusive scan: gbase[b] = #nodes with deg>b ----
__global__ void k_scan(const int* __restrict__ ghist, int* __restrict__ gbase) {
  __shared__ int h[MAXD + 1];
  const int tid = threadIdx.x;
  if (tid <= MAXD) h[tid] = ghist[tid];
  __syncthreads();
  if (tid == 0) {
    int tot = 0;
    for (int b = MAXD; b >= 0; --b) { int c = h[b]; h[b] = tot; tot += c; }
  }
  __syncthreads();
  if (tid <= MAXD) gbase[tid] = h[tid];
}

// ---- two-pass scatter (replaces 30,000 contended global atomics with a
// block-local LDS rank + one global atomicAdd per (block,bucket) to reserve
// a range). Within-bucket order is arbitrary — k_lstm only needs grouping
// by descending bucket (T = cnts_s[0] is still the batch max). ----
__global__ void k_scat2(const int* __restrict__ starts, const int* __restrict__ ends,
                        int* __restrict__ gbase, int* __restrict__ order) {
  __shared__ int lh[MAXD + 1];
  __shared__ int lbase[MAXD + 1];
  const int tid = threadIdx.x;
  if (tid <= MAXD) lh[tid] = 0;
  __syncthreads();
  int n = blockIdx.x * 256 + tid;
  int c = 0, rank = 0;
  if (n < NN) {
    c = ends[n] - starts[n]; c = c > MAXD ? MAXD : c;
    rank = atomicAdd(&lh[c], 1);
  }
  __syncthreads();
  if (tid <= MAXD && lh[tid] > 0) lbase[tid] = atomicAdd(&gbase[tid], lh[tid]);
  __syncthreads();
  if (n < NN) order[lbase[c] + rank] = n;
}

__global__ void k_nbr(const int* __restrict__ src, const int* __restrict__ trg,
                      const int* __restrict__ starts, int* __restrict__ nbr) {
  int e = blockIdx.x * 256 + threadIdx.x;
  if (e >= NE) return;
  int s = src[e];
  int pos = e - starts[s];
  if (pos < MAXD) nbr[s * MAXD + pos] = trg[e];
}

// ---- proj = X @ W_ih.T + (b_ih+b_hh), bf16 MFMA, permuted layout:
// j = g*128 + wv*32 + db*16 + lc  ->  pos = (wv*16+lc)*8 + g*2 + db.
// Weights now loaded pre-converted/pre-swizzled (coalesced 16B/lane). ----
__global__ __launch_bounds__(256)
__attribute__((amdgpu_waves_per_eu(2, 2))) void k_proj(
    const float* __restrict__ x, const short* __restrict__ wih_s,
    const float* __restrict__ b_ih, const float* __restrict__ b_hh,
    short* __restrict__ proj) {
  __shared__ __align__(16) short xs[64 * HPAD];
  const int tid = threadIdx.x;
  const int wv = tid >> 6, lane = tid & 63, lq = lane >> 4, lc = lane & 15;
  const int base = blockIdx.x * 64;

  for (int idx4 = tid; idx4 < 64 * 32; idx4 += 256) {
    int row = idx4 >> 5, k4 = (idx4 & 31) << 2;
    f32x4 v = (f32x4){0.f, 0.f, 0.f, 0.f};
    if (base + row < NN) v = *(const f32x4*)&x[(base + row) * 128 + k4];
    s16x4 p; p[0] = f2bs(v[0]); p[1] = f2bs(v[1]); p[2] = f2bs(v[2]); p[3] = f2bs(v[3]);
    *(s16x4*)&xs[row * HPAD + k4] = p;
  }
  const short8* wihv = (const short8*)wih_s;
  short8 wfrag[4][2][4];
#pragma unroll
  for (int g = 0; g < 4; ++g)
#pragma unroll
    for (int db = 0; db < 2; ++db)
#pragma unroll
      for (int kt = 0; kt < 4; ++kt) {
        short8 w = wihv[(g * 8 + db * 4 + kt) * 256 + tid];
        PIN_AGPR(w);
        wfrag[g][db][kt] = w;
      }
  float bias_v[4][2];
#pragma unroll
  for (int g = 0; g < 4; ++g)
#pragma unroll
    for (int db = 0; db < 2; ++db) {
      int j = g * 128 + wv * 32 + db * 16 + lc;
      bias_v[g][db] = b_ih[j] + b_hh[j];
    }
  __syncthreads();

#pragma unroll
  for (int mt = 0; mt < 4; ++mt) {
    short8 afrag[4];
#pragma unroll
    for (int kt = 0; kt < 4; ++kt)
      afrag[kt] = *(const short8*)&xs[(mt * 16 + lc) * HPAD + kt * 32 + lq * 8];
    f32x4 acc[4][2];
#pragma unroll
    for (int g = 0; g < 4; ++g)
#pragma unroll
      for (int db = 0; db < 2; ++db) {
        float b = bias_v[g][db];
        acc[g][db] = (f32x4){b, b, b, b};
#pragma unroll
        for (int kt = 0; kt < 4; ++kt)
          acc[g][db] = __builtin_amdgcn_mfma_f32_16x16x32_bf16(
              afrag[kt], wfrag[g][db][kt], acc[g][db], 0, 0, 0);
      }
#pragma unroll
    for (int r = 0; r < 4; ++r) {
      int row = base + mt * 16 + lq * 4 + r;
      if (row < NN) {
        short8 w;
        w[0] = f2bs(acc[0][0][r]); w[1] = f2bs(acc[0][1][r]);
        w[2] = f2bs(acc[1][0][r]); w[3] = f2bs(acc[1][1][r]);
        w[4] = f2bs(acc[2][0][r]); w[5] = f2bs(acc[2][1][r]);
        w[6] = f2bs(acc[3][0][r]); w[7] = f2bs(acc[3][1][r]);
        *(short8*)&proj[row * NG + (wv * 16 + lc) * 8] = w;
      }
    }
  }
}

// ---- LSTM: W_hh B-frags AGPR-pinned, loaded pre-swizzled (32 coalesced
// 16B loads replace 64 strided f32x4 loads + 256 f2bs per thread);
// distance-1 prefetch of the proj gather via global_load_lds into a
// wave-private LDS buffer; double-buffered h_s with register copy-forward
// -> one barrier per step. waves_per_eu(2,2): 256-reg total budget =
// 128 AGPR (wfrag) + arch rest. Inner loop unchanged since round 3. ----
__global__ __launch_bounds__(256)
__attribute__((amdgpu_waves_per_eu(2, 2))) void k_lstm(
    const short* __restrict__ whh_s, const short* __restrict__ proj,
    const int* __restrict__ order, const int* __restrict__ starts,
    const int* __restrict__ ends, const int* __restrict__ nbr,
    short* __restrict__ agg) {
  __shared__ __align__(16) short h_s[2][BATCH * HPAD];   // 18432 B
  __shared__ __align__(16) short pbuf[4][8][64 * 8];     // 32768 B, wave-private slots
  __shared__ unsigned short nbr_s[BATCH][MAXD];          // 3072 B
  __shared__ int nodes_s[BATCH];
  __shared__ int cnts_s[BATCH];

  const int tid = threadIdx.x;
  const int wv = tid >> 6, lane = tid & 63, lq = lane >> 4, lc = lane & 15;

  const short8* whhv = (const short8*)whh_s;
  short8 wfrag[4][2][4];
#pragma unroll
  for (int g = 0; g < 4; ++g)
#pragma unroll
    for (int db = 0; db < 2; ++db)
#pragma unroll
      for (int kt = 0; kt < 4; ++kt) {
        short8 w = whhv[(g * 8 + db * 4 + kt) * 256 + tid];
        PIN_AGPR(w);
        wfrag[g][db][kt] = w;
      }

  const int batch = blockIdx.x;
  if (tid < BATCH) {
    int gidx = batch * BATCH + tid;
    int node = 0, c = 0;
    if (gidx < NN) {
      node = order[gidx];
      c = ends[node] - starts[node]; c = c > MAXD ? MAXD : c;
    }
    nodes_s[tid] = node;
    cnts_s[tid] = c;
  }
  __syncthreads();
  for (int idx = tid; idx < BATCH * HPAD / 2; idx += 256)
    ((int*)h_s[0])[idx] = 0;
  for (int idx = tid; idx < BATCH * MAXD; idx += 256) {
    int m = idx / MAXD, p = idx - m * MAXD;
    nbr_s[m][p] = (unsigned short)nbr[nodes_s[m] * MAXD + p];
  }
  __syncthreads();
  const int T = cnts_s[0];  // descending-bucket grouping -> batch max

  // counts packed 4-per-int (each <= 48 fits in 8 bits)
  int cp[2];
#pragma unroll
  for (int mt = 0; mt < 2; ++mt) {
    int p = 0;
#pragma unroll
    for (int r = 0; r < 4; ++r) p |= cnts_s[mt * 16 + lq * 4 + r] << (r * 8);
    cp[mt] = p;
  }

  float c_v[2][2][4];
  s16x4 hvp[2][2];  // last-written h (bf16) for copy-forward of frozen rows
#pragma unroll
  for (int mt = 0; mt < 2; ++mt)
#pragma unroll
    for (int db = 0; db < 2; ++db) {
#pragma unroll
      for (int r = 0; r < 4; ++r) c_v[mt][db][r] = 0.0f;
      hvp[mt][db] = (s16x4){0, 0, 0, 0};
    }

  const int pcol = (wv * 16 + lc) * 8;
  if (T > 0) {  // prologue: async-gather t=0 slices into pbuf
#pragma unroll
    for (int mt = 0; mt < 2; ++mt)
#pragma unroll
      for (int r = 0; r < 4; ++r) {
        int m = mt * 16 + lq * 4 + r;
        int nb_i = (0 < ((cp[mt] >> (r * 8)) & 255)) ? (int)nbr_s[m][0] : 0;
        gl_lds16(&proj[nb_i * NG + pcol], &pbuf[wv][mt * 4 + r][0]);
      }
  }

  for (int t = 0; t < T; ++t) {
    __syncthreads();  // drains prefetch (vmcnt) + makes h writes visible
    const short* hb = h_s[t & 1];
    short* hw = h_s[(t + 1) & 1];
    const int tn = t + 1;
    const int ts = tn < MAXD ? tn : 0;
#pragma unroll
    for (int mt = 0; mt < 2; ++mt) {
      // consume this step's gathered slices (wave-private slots)
      short8 pv[4];
#pragma unroll
      for (int r = 0; r < 4; ++r)
        pv[r] = *(const short8*)&pbuf[wv][mt * 4 + r][lane * 8];
      f32x4 acc[4][2];
#pragma unroll
      for (int g = 0; g < 4; ++g)
#pragma unroll
        for (int db = 0; db < 2; ++db)
#pragma unroll
          for (int r = 0; r < 4; ++r)
            acc[g][db][r] = bs2f(pv[r][g * 2 + db]);  // x-part + bias
      __builtin_amdgcn_sched_barrier(0);  // pv fully consumed before overwrite
      if (tn < T) {  // prefetch t+1 into the same (now free) slots
#pragma unroll
        for (int r = 0; r < 4; ++r) {
          int m = mt * 16 + lq * 4 + r;
          int nb_i = (tn < ((cp[mt] >> (r * 8)) & 255)) ? (int)nbr_s[m][ts] : 0;
          gl_lds16(&proj[nb_i * NG + pcol], &pbuf[wv][mt * 4 + r][0]);
        }
      }
      __builtin_amdgcn_sched_barrier(0);  // keep prefetch issue early
      short8 afrag[4];
#pragma unroll
      for (int kt = 0; kt < 4; ++kt)
        afrag[kt] = *(const short8*)&hb[(mt * 16 + lc) * HPAD + kt * 32 + lq * 8];
#pragma unroll
      for (int g = 0; g < 4; ++g)
#pragma unroll
        for (int db = 0; db < 2; ++db)
#pragma unroll
          for (int kt = 0; kt < 4; ++kt)
            acc[g][db] = __builtin_amdgcn_mfma_f32_16x16x32_bf16(
                afrag[kt], wfrag[g][db][kt], acc[g][db], 0, 0, 0);
#pragma unroll
      for (int db = 0; db < 2; ++db)
#pragma unroll
        for (int r = 0; r < 4; ++r) {
          float iv = sigf(acc[0][db][r]);
          float fv = sigf(acc[1][db][r]);
          float gv = tanh_(acc[2][db][r]);
          float ov = sigf(acc[3][db][r]);
          float c2 = fv * c_v[mt][db][r] + iv * gv;
          float h2 = ov * tanh_(c2);
          if (t < ((cp[mt] >> (r * 8)) & 255)) {
            c_v[mt][db][r] = c2;
            hvp[mt][db][r] = f2bs(h2);
          }
        }
      // unconditional write of (new or carried) h into the other buffer
#pragma unroll
      for (int db = 0; db < 2; ++db)
#pragma unroll
        for (int r = 0; r < 4; ++r)
          hw[(mt * 16 + lq * 4 + r) * HPAD + wv * 32 + db * 16 + lc] =
              hvp[mt][db][r];
    }
  }
  __syncthreads();  // last step's h writes visible
  const short* hf = h_s[T & 1];
  for (int idx = tid; idx < BATCH * 128; idx += 256) {
    int m = idx >> 7, d = idx & 127;
    if (batch * BATCH + m < NN) agg[nodes_s[m] * 128 + d] = hf[m * HPAD + d];
  }
}

// ---- out = [x | h] @ W_out, bf16 MFMA; weights pre-swizzled (16 coalesced
// 16B loads replace 128 scalar f32 loads per thread) ----
__global__ __launch_bounds__(256, 2) void k_out(
    const float* __restrict__ x, const short* __restrict__ agg,
    const short* __restrict__ wout_s, float* __restrict__ out) {
  __shared__ __align__(16) short xs[64 * 272];
  const int tid = threadIdx.x;
  const int wv = tid >> 6, lane = tid & 63, lq = lane >> 4, lc = lane & 15;
  const int base = blockIdx.x * 64;

  for (int idx4 = tid; idx4 < 64 * 32; idx4 += 256) {
    int row = idx4 >> 5, k4 = (idx4 & 31) << 2;
    f32x4 v = (f32x4){0.f, 0.f, 0.f, 0.f};
    if (base + row < NN) v = *(const f32x4*)&x[(base + row) * 128 + k4];
    s16x4 p; p[0] = f2bs(v[0]); p[1] = f2bs(v[1]); p[2] = f2bs(v[2]); p[3] = f2bs(v[3]);
    *(s16x4*)&xs[row * 272 + k4] = p;
    s16x4 a = (s16x4){0, 0, 0, 0};
    if (base + row < NN) a = *(const s16x4*)&agg[(base + row) * 128 + k4];
    *(s16x4*)&xs[row * 272 + 128 + k4] = a;
  }
  const short8* wov = (const short8*)wout_s;
  short8 wf[2][8];
#pragma unroll
  for (int db = 0; db < 2; ++db)
#pragma unroll
    for (int kt = 0; kt < 8; ++kt)
      wf[db][kt] = wov[(db * 8 + kt) * 256 + tid];
  __syncthreads();

#pragma unroll
  for (int mt = 0; mt < 4; ++mt) {
    short8 afrag[8];
#pragma unroll
    for (int kt = 0; kt < 8; ++kt)
      afrag[kt] = *(const short8*)&xs[(mt * 16 + lc) * 272 + kt * 32 + lq * 8];
    f32x4 acc[2];
#pragma unroll
    for (int db = 0; db < 2; ++db) {
      acc[db] = (f32x4){0.f, 0.f, 0.f, 0.f};
#pragma unroll
      for (int kt = 0; kt < 8; ++kt)
        acc[db] = __builtin_amdgcn_mfma_f32_16x16x32_bf16(
            afrag[kt], wf[db][kt], acc[db], 0, 0, 0);
    }
#pragma unroll
    for (int db = 0; db < 2; ++db)
#pragma unroll
      for (int r = 0; r < 4; ++r) {
        int row = base + mt * 16 + lq * 4 + r;
        if (row < NN)
          out[row * 128 + wv * 32 + db * 16 + lc] = acc[db][r];
      }
  }
}

extern "C" void kernel_launch(void* const* d_in, const int* in_sizes, int n_in,
                              void* d_out, int out_size, void* d_ws,
                              size_t ws_size, hipStream_t stream) {
  (void)in_sizes; (void)n_in; (void)out_size; (void)ws_size;
  const float* x     = (const float*)d_in[0];
  const float* W_ih  = (const float*)d_in[1];
  const float* W_hh  = (const float*)d_in[2];
  const float* b_ih  = (const float*)d_in[3];
  const float* b_hh  = (const float*)d_in[4];
  const float* W_out = (const float*)d_in[5];
  const int*   esrc  = (const int*)d_in[6];
  const int*   etrg  = (const int*)d_in[7];
  float* out = (float*)d_out;
  char* ws = (char*)d_ws;

  int*   starts = (int*)(ws + 0);          // 120,000 B
  int*   ends   = (int*)(ws + 120064);     // 120,000 B
  int*   ghist  = (int*)(ws + 240128);     // 196 B (zeroed by memset)
  int*   order  = (int*)(ws + 240384);     // 120,000 B
  int*   nbr    = (int*)(ws + 360448);     // 5,760,000 B
  short* proj   = (short*)(ws + 6382848);  // 30,720,000 B (bf16, permuted cols)
  short* agg    = (short*)(ws + 37102848); // 7,680,000 B (bf16)
  short* wih_s  = (short*)(ws + 44782848); // 131,072 B (bf16, frag-swizzled)
  short* whh_s  = (short*)(ws + 44913920); // 131,072 B
  short* wout_s = (short*)(ws + 45045760); // 65,536 B
  int*   gbase  = (int*)(ws + 45111296);   // 196 B (written by k_scan)

  (void)hipMemsetAsync(d_ws, 0, 240384, stream);  // starts + ends + ghist

  k_edges_wcvt<<<EDGE_BLKS + 80, 256, 0, stream>>>(esrc, starts, ends, W_ih,
                                                   W_hh, W_out, wih_s, whh_s,
                                                   wout_s);
  k_hist <<<118, 256, 0, stream>>>(starts, ends, ghist);
  k_scan <<<1, 64, 0, stream>>>(ghist, gbase);
  k_scat2<<<118, 256, 0, stream>>>(starts, ends, gbase, order);
  k_nbr  <<<1875, 256, 0, stream>>>(esrc, etrg, starts, nbr);
  k_proj <<<NGB, 256, 0, stream>>>(x, wih_s, b_ih, b_hh, proj);
  k_lstm <<<NB, 256, 0, stream>>>(whh_s, proj, order, starts, ends, nbr, agg);
  k_out  <<<NGB, 256, 0, stream>>>(x, agg, wout_s, out);
}

// Round 5
// 249.993 us; speedup vs baseline: 1.6842x; 1.0403x over previous
//
#include <hip/hip_runtime.h>

#define NN 30000
#define NE 480000
#define NG 512
#define MAXD 48
#define BATCH 32
#define NB 938    // ceil(30000/32)
#define HPAD 144  // h_s row stride in shorts
#define NGB 469   // ceil(30000/64) for the 64-row GEMM kernels

typedef __attribute__((ext_vector_type(8))) short short8;
typedef __attribute__((ext_vector_type(4))) short s16x4;
typedef __attribute__((ext_vector_type(4))) float f32x4;
typedef __attribute__((ext_vector_type(4))) int i32x4;

#define L2E 1.44269504089f   // log2(e)
#define L2E2 2.88539008178f  // 2*log2(e)

static __device__ __forceinline__ short f2bs(float f) {
  unsigned u = __builtin_bit_cast(unsigned, f);
  u = (u + 0x7fffu + ((u >> 16) & 1u)) >> 16;
  return (short)u;
}
// async 16B-per-lane gather into LDS: dest = ldsbase + lane*16
static __device__ __forceinline__ void gl_lds16(const short* g, short* l) {
  __builtin_amdgcn_global_load_lds(
      (const __attribute__((address_space(1))) void*)g,
      (__attribute__((address_space(3))) void*)l, 16, 0, 0);
}

// Pin a bf16x8 MFMA B-fragment to AGPRs (gfx950 unified RF: MFMA reads A/B
// from AGPR). Round-3 rocprof verified this kills the arch-VGPR spill:
// k_lstm WRITE_SIZE 107,866 KB -> 7,500 KB. Keep the builtin MFMA
// (compiler-managed hazards); a full inline-asm MFMA broke the hazard
// recognizer in round 1 (absmax 0.47).
#define PIN_AGPR(w_) asm("" : "+a"(w_))

// ---- prep: segment starts/ends via boundary detection (src sorted) FUSED
// with one-time weight bf16 pre-conversion into per-thread fragment layout.
// NEW (r5): weights are pre-scaled into the exp2 domain — rows of gates
// i,f,o by log2(e), gate g by 2*log2(e) — so k_lstm's activations use raw
// v_exp_f32 (exp2) with no per-element argument scaling. Biases get the
// same scale in k_proj; proj therefore stores SCALED pre-activations,
// consumed only by k_lstm in the same domain. ----
#define EDGE_BLKS 1875
__global__ void k_edges_wcvt(const int* __restrict__ src, int* __restrict__ starts,
                             int* __restrict__ ends,
                             const float* __restrict__ W_ih,
                             const float* __restrict__ W_hh,
                             const float* __restrict__ Wout,
                             short* __restrict__ wih_s, short* __restrict__ whh_s,
                             short* __restrict__ wout_s) {
  const int b = blockIdx.x, tid = threadIdx.x;
  if (b < EDGE_BLKS) {
    int e = b * 256 + tid;
    if (e >= NE) return;
    int s = src[e];
    if (e == 0 || src[e - 1] != s) starts[s] = e;
    if (e == NE - 1 || src[e + 1] != s) ends[s] = e + 1;
    return;
  }
  const int f = b - EDGE_BLKS;  // 0..79
  const int wv = tid >> 6, lq = (tid >> 4) & 3, lc = tid & 15;
  if (f < 64) {
    const float* W = (f < 32) ? W_ih : W_hh;
    short* dst = (f < 32) ? wih_s : whh_s;
    const int ff = f & 31;
    const int g = ff >> 3, db = (ff >> 2) & 1, kt = ff & 3;
    const float s = (g == 2) ? L2E2 : L2E;  // exp2-domain pre-scale
    const float* p = &W[(g * 128 + wv * 32 + db * 16 + lc) * 128 + kt * 32 + lq * 8];
    f32x4 a = *(const f32x4*)p;
    f32x4 c = *(const f32x4*)(p + 4);
    short8 w;
    w[0] = f2bs(a[0] * s); w[1] = f2bs(a[1] * s); w[2] = f2bs(a[2] * s); w[3] = f2bs(a[3] * s);
    w[4] = f2bs(c[0] * s); w[5] = f2bs(c[1] * s); w[6] = f2bs(c[2] * s); w[7] = f2bs(c[3] * s);
    *(short8*)&dst[(ff * 256 + tid) * 8] = w;
  } else {
    const int fo = f - 64;  // 0..15 (W_out: NOT scaled)
    const int db = fo >> 3, kt = fo & 7;
    short8 w;
#pragma unroll
    for (int jj = 0; jj < 8; ++jj)
      w[jj] = f2bs(Wout[(kt * 32 + lq * 8 + jj) * 128 + wv * 32 + db * 16 + lc]);
    *(short8*)&wout_s[(fo * 256 + tid) * 8] = w;
  }
}

// ---- neighbor list build FUSED with the degree histogram (same dependency
// level: both only need starts/ends). Blocks >=118 skip the hist flush. ----
__global__ void k_nbr_hist(const int* __restrict__ src, const int* __restrict__ trg,
                           const int* __restrict__ starts, const int* __restrict__ ends,
                           int* __restrict__ nbr, int* __restrict__ ghist) {
  __shared__ int h[MAXD + 1];
  const int tid = threadIdx.x;
  if (tid <= MAXD) h[tid] = 0;
  __syncthreads();
  int e = blockIdx.x * 256 + tid;
  if (e < NE) {
    int s = src[e];
    int pos = e - starts[s];
    if (pos < MAXD) nbr[s * MAXD + pos] = trg[e];
  }
  if (e < NN) {
    int c = ends[e] - starts[e]; c = c > MAXD ? MAXD : c;
    atomicAdd(&h[c], 1);
  }
  __syncthreads();
  if (tid <= MAXD && h[tid] > 0) atomicAdd(&ghist[tid], h[tid]);
}

// ---- scatter with INLINE descending-bucket scan (replaces the separate
// k_scan launch: every block redoes the trivial 49-bucket scan from the
// complete ghist; gclaim[] global counters — zeroed by the launch-side
// memset — hand out within-bucket ranges). Within-bucket order arbitrary;
// k_lstm only needs descending-bucket grouping (T = cnts_s[0] = batch max). ----
__global__ void k_scat2(const int* __restrict__ starts, const int* __restrict__ ends,
                        const int* __restrict__ ghist, int* __restrict__ gclaim,
                        int* __restrict__ order) {
  __shared__ int lh[MAXD + 1];
  __shared__ int lbase[MAXD + 1];
  __shared__ int sbase[MAXD + 1];
  const int tid = threadIdx.x;
  if (tid <= MAXD) lh[tid] = 0;
  __syncthreads();
  int n = blockIdx.x * 256 + tid;
  int c = 0, rank = 0;
  if (n < NN) {
    c = ends[n] - starts[n]; c = c > MAXD ? MAXD : c;
    rank = atomicAdd(&lh[c], 1);
  }
  if (tid == 0) {
    int tot = 0;
    for (int b = MAXD; b >= 0; --b) { sbase[b] = tot; tot += ghist[b]; }
  }
  __syncthreads();
  if (tid <= MAXD && lh[tid] > 0)
    lbase[tid] = sbase[tid] + atomicAdd(&gclaim[tid], lh[tid]);
  __syncthreads();
  if (n < NN) order[lbase[c] + rank] = n;
}

// ---- proj = X @ W_ih.T + (b_ih+b_hh), bf16 MFMA, permuted layout:
// j = g*128 + wv*32 + db*16 + lc  ->  pos = (wv*16+lc)*8 + g*2 + db.
// Bias gets the same exp2-domain per-gate scale as the weights. ----
__global__ __launch_bounds__(256)
__attribute__((amdgpu_waves_per_eu(2, 2))) void k_proj(
    const float* __restrict__ x, const short* __restrict__ wih_s,
    const float* __restrict__ b_ih, const float* __restrict__ b_hh,
    short* __restrict__ proj) {
  __shared__ __align__(16) short xs[64 * HPAD];
  const int tid = threadIdx.x;
  const int wv = tid >> 6, lane = tid & 63, lq = lane >> 4, lc = lane & 15;
  const int base = blockIdx.x * 64;

  for (int idx4 = tid; idx4 < 64 * 32; idx4 += 256) {
    int row = idx4 >> 5, k4 = (idx4 & 31) << 2;
    f32x4 v = (f32x4){0.f, 0.f, 0.f, 0.f};
    if (base + row < NN) v = *(const f32x4*)&x[(base + row) * 128 + k4];
    s16x4 p; p[0] = f2bs(v[0]); p[1] = f2bs(v[1]); p[2] = f2bs(v[2]); p[3] = f2bs(v[3]);
    *(s16x4*)&xs[row * HPAD + k4] = p;
  }
  const short8* wihv = (const short8*)wih_s;
  short8 wfrag[4][2][4];
#pragma unroll
  for (int g = 0; g < 4; ++g)
#pragma unroll
    for (int db = 0; db < 2; ++db)
#pragma unroll
      for (int kt = 0; kt < 4; ++kt) {
        short8 w = wihv[(g * 8 + db * 4 + kt) * 256 + tid];
        PIN_AGPR(w);
        wfrag[g][db][kt] = w;
      }
  float bias_v[4][2];
#pragma unroll
  for (int g = 0; g < 4; ++g)
#pragma unroll
    for (int db = 0; db < 2; ++db) {
      int j = g * 128 + wv * 32 + db * 16 + lc;
      bias_v[g][db] = (b_ih[j] + b_hh[j]) * ((g == 2) ? L2E2 : L2E);
    }
  __syncthreads();

#pragma unroll
  for (int mt = 0; mt < 4; ++mt) {
    short8 afrag[4];
#pragma unroll
    for (int kt = 0; kt < 4; ++kt)
      afrag[kt] = *(const short8*)&xs[(mt * 16 + lc) * HPAD + kt * 32 + lq * 8];
    f32x4 acc[4][2];
#pragma unroll
    for (int g = 0; g < 4; ++g)
#pragma unroll
      for (int db = 0; db < 2; ++db) {
        float b = bias_v[g][db];
        acc[g][db] = (f32x4){b, b, b, b};
#pragma unroll
        for (int kt = 0; kt < 4; ++kt)
          acc[g][db] = __builtin_amdgcn_mfma_f32_16x16x32_bf16(
              afrag[kt], wfrag[g][db][kt], acc[g][db], 0, 0, 0);
      }
#pragma unroll
    for (int r = 0; r < 4; ++r) {
      int row = base + mt * 16 + lq * 4 + r;
      if (row < NN) {
        short8 w;
        w[0] = f2bs(acc[0][0][r]); w[1] = f2bs(acc[0][1][r]);
        w[2] = f2bs(acc[1][0][r]); w[3] = f2bs(acc[1][1][r]);
        w[4] = f2bs(acc[2][0][r]); w[5] = f2bs(acc[2][1][r]);
        w[6] = f2bs(acc[3][0][r]); w[7] = f2bs(acc[3][1][r]);
        *(short8*)&proj[row * NG + (wv * 16 + lc) * 8] = w;
      }
    }
  }
}

// ---- LSTM: W_hh B-frags AGPR-pinned, pre-swizzled, pre-scaled to the exp2
// domain. Gate math (r5): raw v_exp_f32 (no arg muls) + fused denominators
//   i*g        = (Eg-1) * rcp((1+exp2(-yi)) * (1+Eg)),  Eg = exp2(min(yg,125))
//   o*tanh(c2) = (Ec-1) * rcp((1+exp2(-yo)) * (1+Ec)),  Ec = exp2(min(2*log2e*c2,125))
// -> 8 trans/element (was 10: 5 exp + 5 rcp) and no __expf scaling muls.
// Overflow-audited: clamps keep (E-1) finite; every inf path collapses via
// rcp(inf)=0 to the correct saturated value (no NaN). proj x-part unpacked
// with the shl16 / and-mask bf16-pair trick (1 VALU/element). ----
__global__ __launch_bounds__(256)
__attribute__((amdgpu_waves_per_eu(2, 2))) void k_lstm(
    const short* __restrict__ whh_s, const short* __restrict__ proj,
    const int* __restrict__ order, const int* __restrict__ starts,
    const int* __restrict__ ends, const int* __restrict__ nbr,
    short* __restrict__ agg) {
  __shared__ __align__(16) short h_s[2][BATCH * HPAD];   // 18432 B
  __shared__ __align__(16) short pbuf[4][8][64 * 8];     // 32768 B, wave-private slots
  __shared__ unsigned short nbr_s[BATCH][MAXD];          // 3072 B
  __shared__ int nodes_s[BATCH];
  __shared__ int cnts_s[BATCH];

  const int tid = threadIdx.x;
  const int wv = tid >> 6, lane = tid & 63, lq = lane >> 4, lc = lane & 15;

  const short8* whhv = (const short8*)whh_s;
  short8 wfrag[4][2][4];
#pragma unroll
  for (int g = 0; g < 4; ++g)
#pragma unroll
    for (int db = 0; db < 2; ++db)
#pragma unroll
      for (int kt = 0; kt < 4; ++kt) {
        short8 w = whhv[(g * 8 + db * 4 + kt) * 256 + tid];
        PIN_AGPR(w);
        wfrag[g][db][kt] = w;
      }

  const int batch = blockIdx.x;
  if (tid < BATCH) {
    int gidx = batch * BATCH + tid;
    int node = 0, c = 0;
    if (gidx < NN) {
      node = order[gidx];
      c = ends[node] - starts[node]; c = c > MAXD ? MAXD : c;
    }
    nodes_s[tid] = node;
    cnts_s[tid] = c;
  }
  __syncthreads();
  for (int idx = tid; idx < BATCH * HPAD / 2; idx += 256)
    ((int*)h_s[0])[idx] = 0;
  for (int idx = tid; idx < BATCH * MAXD; idx += 256) {
    int m = idx / MAXD, p = idx - m * MAXD;
    nbr_s[m][p] = (unsigned short)nbr[nodes_s[m] * MAXD + p];
  }
  __syncthreads();
  const int T = cnts_s[0];  // descending-bucket grouping -> batch max

  // counts packed 4-per-int (each <= 48 fits in 8 bits)
  int cp[2];
#pragma unroll
  for (int mt = 0; mt < 2; ++mt) {
    int p = 0;
#pragma unroll
    for (int r = 0; r < 4; ++r) p |= cnts_s[mt * 16 + lq * 4 + r] << (r * 8);
    cp[mt] = p;
  }

  float c_v[2][2][4];
  s16x4 hvp[2][2];  // last-written h (bf16) for copy-forward of frozen rows
#pragma unroll
  for (int mt = 0; mt < 2; ++mt)
#pragma unroll
    for (int db = 0; db < 2; ++db) {
#pragma unroll
      for (int r = 0; r < 4; ++r) c_v[mt][db][r] = 0.0f;
      hvp[mt][db] = (s16x4){0, 0, 0, 0};
    }

  const int pcol = (wv * 16 + lc) * 8;
  if (T > 0) {  // prologue: async-gather t=0 slices into pbuf
#pragma unroll
    for (int mt = 0; mt < 2; ++mt)
#pragma unroll
      for (int r = 0; r < 4; ++r) {
        int m = mt * 16 + lq * 4 + r;
        int nb_i = (0 < ((cp[mt] >> (r * 8)) & 255)) ? (int)nbr_s[m][0] : 0;
        gl_lds16(&proj[nb_i * NG + pcol], &pbuf[wv][mt * 4 + r][0]);
      }
  }

  for (int t = 0; t < T; ++t) {
    __syncthreads();  // drains prefetch (vmcnt) + makes h writes visible
    const short* hb = h_s[t & 1];
    short* hw = h_s[(t + 1) & 1];
    const int tn = t + 1;
    const int ts = tn < MAXD ? tn : 0;
#pragma unroll
    for (int mt = 0; mt < 2; ++mt) {
      // consume this step's gathered slices (wave-private slots)
      i32x4 pvi[4];
#pragma unroll
      for (int r = 0; r < 4; ++r)
        pvi[r] = *(const i32x4*)&pbuf[wv][mt * 4 + r][lane * 8];
      f32x4 acc[4][2];
#pragma unroll
      for (int g = 0; g < 4; ++g)
#pragma unroll
        for (int r = 0; r < 4; ++r) {
          unsigned u = (unsigned)pvi[r][g];  // two bf16: db0=lo, db1=hi
          acc[g][0][r] = __builtin_bit_cast(float, u << 16);
          acc[g][1][r] = __builtin_bit_cast(float, u & 0xffff0000u);
        }
      __builtin_amdgcn_sched_barrier(0);  // pvi fully consumed before overwrite
      if (tn < T) {  // prefetch t+1 into the same (now free) slots
#pragma unroll
        for (int r = 0; r < 4; ++r) {
          int m = mt * 16 + lq * 4 + r;
          int nb_i = (tn < ((cp[mt] >> (r * 8)) & 255)) ? (int)nbr_s[m][ts] : 0;
          gl_lds16(&proj[nb_i * NG + pcol], &pbuf[wv][mt * 4 + r][0]);
        }
      }
      __builtin_amdgcn_sched_barrier(0);  // keep prefetch issue early
      short8 afrag[4];
#pragma unroll
      for (int kt = 0; kt < 4; ++kt)
        afrag[kt] = *(const short8*)&hb[(mt * 16 + lc) * HPAD + kt * 32 + lq * 8];
#pragma unroll
      for (int g = 0; g < 4; ++g)
#pragma unroll
        for (int db = 0; db < 2; ++db)
#pragma unroll
          for (int kt = 0; kt < 4; ++kt)
            acc[g][db] = __builtin_amdgcn_mfma_f32_16x16x32_bf16(
                afrag[kt], wfrag[g][db][kt], acc[g][db], 0, 0, 0);
#pragma unroll
      for (int db = 0; db < 2; ++db)
#pragma unroll
        for (int r = 0; r < 4; ++r) {
          float Ei = __builtin_amdgcn_exp2f(-acc[0][db][r]);
          float Eg = __builtin_amdgcn_exp2f(fminf(acc[2][db][r], 125.f));
          float ig = (Eg - 1.f) *
                     __builtin_amdgcn_rcpf((1.f + Ei) * (1.f + Eg));
          float fv = __builtin_amdgcn_rcpf(
              1.f + __builtin_amdgcn_exp2f(-acc[1][db][r]));
          float c2 = fv * c_v[mt][db][r] + ig;
          float Eo = __builtin_amdgcn_exp2f(-acc[3][db][r]);
          float Ec = __builtin_amdgcn_exp2f(fminf(c2 * L2E2, 125.f));
          float h2 = (Ec - 1.f) *
                     __builtin_amdgcn_rcpf((1.f + Eo) * (1.f + Ec));
          if (t < ((cp[mt] >> (r * 8)) & 255)) {
            c_v[mt][db][r] = c2;
            hvp[mt][db][r] = f2bs(h2);
          }
        }
      // unconditional write of (new or carried) h into the other buffer
#pragma unroll
      for (int db = 0; db < 2; ++db)
#pragma unroll
        for (int r = 0; r < 4; ++r)
          hw[(mt * 16 + lq * 4 + r) * HPAD + wv * 32 + db * 16 + lc] =
              hvp[mt][db][r];
    }
  }
  __syncthreads();  // last step's h writes visible
  const short* hf = h_s[T & 1];
  for (int idx = tid; idx < BATCH * 128; idx += 256) {
    int m = idx >> 7, d = idx & 127;
    if (batch * BATCH + m < NN) agg[nodes_s[m] * 128 + d] = hf[m * HPAD + d];
  }
}

// ---- out = [x | h] @ W_out, bf16 MFMA; weights pre-swizzled ----
__global__ __launch_bounds__(256, 2) void k_out(
    const float* __restrict__ x, const short* __restrict__ agg,
    const short* __restrict__ wout_s, float* __restrict__ out) {
  __shared__ __align__(16) short xs[64 * 272];
  const int tid = threadIdx.x;
  const int wv = tid >> 6, lane = tid & 63, lq = lane >> 4, lc = lane & 15;
  const int base = blockIdx.x * 64;

  for (int idx4 = tid; idx4 < 64 * 32; idx4 += 256) {
    int row = idx4 >> 5, k4 = (idx4 & 31) << 2;
    f32x4 v = (f32x4){0.f, 0.f, 0.f, 0.f};
    if (base + row < NN) v = *(const f32x4*)&x[(base + row) * 128 + k4];
    s16x4 p; p[0] = f2bs(v[0]); p[1] = f2bs(v[1]); p[2] = f2bs(v[2]); p[3] = f2bs(v[3]);
    *(s16x4*)&xs[row * 272 + k4] = p;
    s16x4 a = (s16x4){0, 0, 0, 0};
    if (base + row < NN) a = *(const s16x4*)&agg[(base + row) * 128 + k4];
    *(s16x4*)&xs[row * 272 + 128 + k4] = a;
  }
  const short8* wov = (const short8*)wout_s;
  short8 wf[2][8];
#pragma unroll
  for (int db = 0; db < 2; ++db)
#pragma unroll
    for (int kt = 0; kt < 8; ++kt)
      wf[db][kt] = wov[(db * 8 + kt) * 256 + tid];
  __syncthreads();

#pragma unroll
  for (int mt = 0; mt < 4; ++mt) {
    short8 afrag[8];
#pragma unroll
    for (int kt = 0; kt < 8; ++kt)
      afrag[kt] = *(const short8*)&xs[(mt * 16 + lc) * 272 + kt * 32 + lq * 8];
    f32x4 acc[2];
#pragma unroll
    for (int db = 0; db < 2; ++db) {
      acc[db] = (f32x4){0.f, 0.f, 0.f, 0.f};
#pragma unroll
      for (int kt = 0; kt < 8; ++kt)
        acc[db] = __builtin_amdgcn_mfma_f32_16x16x32_bf16(
            afrag[kt], wf[db][kt], acc[db], 0, 0, 0);
    }
#pragma unroll
    for (int db = 0; db < 2; ++db)
#pragma unroll
      for (int r = 0; r < 4; ++r) {
        int row = base + mt * 16 + lq * 4 + r;
        if (row < NN)
          out[row * 128 + wv * 32 + db * 16 + lc] = acc[db][r];
      }
  }
}

extern "C" void kernel_launch(void* const* d_in, const int* in_sizes, int n_in,
                              void* d_out, int out_size, void* d_ws,
                              size_t ws_size, hipStream_t stream) {
  (void)in_sizes; (void)n_in; (void)out_size; (void)ws_size;
  const float* x     = (const float*)d_in[0];
  const float* W_ih  = (const float*)d_in[1];
  const float* W_hh  = (const float*)d_in[2];
  const float* b_ih  = (const float*)d_in[3];
  const float* b_hh  = (const float*)d_in[4];
  const float* W_out = (const float*)d_in[5];
  const int*   esrc  = (const int*)d_in[6];
  const int*   etrg  = (const int*)d_in[7];
  float* out = (float*)d_out;
  char* ws = (char*)d_ws;

  int*   starts = (int*)(ws + 0);          // 120,000 B
  int*   ends   = (int*)(ws + 120064);     // 120,000 B
  int*   ghist  = (int*)(ws + 240128);     // 196 B (zeroed by memset)
  int*   gclaim = (int*)(ws + 240384);     // 196 B (zeroed by memset)
  int*   order  = (int*)(ws + 240640);     // 120,000 B
  int*   nbr    = (int*)(ws + 360704);     // 5,760,000 B
  short* proj   = (short*)(ws + 6120704);  // 30,720,000 B (bf16, scaled, permuted)
  short* agg    = (short*)(ws + 36840704); // 7,680,000 B (bf16)
  short* wih_s  = (short*)(ws + 44520704); // 131,072 B (bf16, frag-swizzled, scaled)
  short* whh_s  = (short*)(ws + 44651776); // 131,072 B
  short* wout_s = (short*)(ws + 44782848); // 65,536 B

  (void)hipMemsetAsync(d_ws, 0, 240640, stream);  // starts+ends+ghist+gclaim

  k_edges_wcvt<<<EDGE_BLKS + 80, 256, 0, stream>>>(esrc, starts, ends, W_ih,
                                                   W_hh, W_out, wih_s, whh_s,
                                                   wout_s);
  k_nbr_hist<<<1875, 256, 0, stream>>>(esrc, etrg, starts, ends, nbr, ghist);
  k_scat2<<<118, 256, 0, stream>>>(starts, ends, ghist, gclaim, order);
  k_proj <<<NGB, 256, 0, stream>>>(x, wih_s, b_ih, b_hh, proj);
  k_lstm <<<NB, 256, 0, stream>>>(whh_s, proj, order, starts, ends, nbr, agg);
  k_out  <<<NGB, 256, 0, stream>>>(x, agg, wout_s, out);
}

// Round 6
// 237.234 us; speedup vs baseline: 1.7747x; 1.0538x over previous
//
#include <hip/hip_runtime.h>

#define NN 30000
#define NE 480000
#define NG 512
#define MAXD 48
#define BATCH 32
#define NB 938    // ceil(30000/32)
#define HPAD 144  // h_s row stride in shorts
#define NGB 469   // ceil(30000/64) for the 64-row GEMM kernel (k_proj)
#define XTS 272   // [x|h] tile row stride in shorts (tail GEMM)

typedef __attribute__((ext_vector_type(8))) short short8;
typedef __attribute__((ext_vector_type(4))) short s16x4;
typedef __attribute__((ext_vector_type(4))) float f32x4;
typedef __attribute__((ext_vector_type(4))) int i32x4;

#define L2E 1.44269504089f   // log2(e)
#define L2E2 2.88539008178f  // 2*log2(e)

static __device__ __forceinline__ short f2bs(float f) {
  unsigned u = __builtin_bit_cast(unsigned, f);
  u = (u + 0x7fffu + ((u >> 16) & 1u)) >> 16;
  return (short)u;
}
// packed f32->bf16 (RNE, same rounding as f2bs): lo = S0, hi = S1.
// Plain-VALU inline asm is safe (hw-interlocked); only MFMA asm was not (r1).
static __device__ __forceinline__ unsigned cvtpk(float lo, float hi) {
  unsigned r;
  asm("v_cvt_pk_bf16_f32 %0, %1, %2" : "=v"(r) : "v"(lo), "v"(hi));
  return r;
}
// async 16B-per-lane gather into LDS: dest = ldsbase + lane*16
static __device__ __forceinline__ void gl_lds16(const short* g, short* l) {
  __builtin_amdgcn_global_load_lds(
      (const __attribute__((address_space(1))) void*)g,
      (__attribute__((address_space(3))) void*)l, 16, 0, 0);
}

// Pin a bf16x8 MFMA B-fragment to AGPRs (gfx950 unified RF: MFMA reads A/B
// from AGPR). Round-3 rocprof verified this kills the arch-VGPR spill:
// k_lstm WRITE_SIZE 107,866 KB -> 7,500 KB. Keep the builtin MFMA
// (compiler-managed hazards); full inline-asm MFMA broke the hazard
// recognizer in round 1 (absmax 0.47).
#define PIN_AGPR(w_) asm("" : "+a"(w_))

// ---- prep: segment starts/ends via boundary detection (src sorted) FUSED
// with one-time weight bf16 pre-conversion into per-thread fragment layout.
// Weights pre-scaled into the exp2 domain (gates i,f,o by log2e, g by
// 2*log2e) so k_lstm uses raw v_exp_f32. ----
#define EDGE_BLKS 1875
__global__ void k_edges_wcvt(const int* __restrict__ src, int* __restrict__ starts,
                             int* __restrict__ ends,
                             const float* __restrict__ W_ih,
                             const float* __restrict__ W_hh,
                             const float* __restrict__ Wout,
                             short* __restrict__ wih_s, short* __restrict__ whh_s,
                             short* __restrict__ wout_s) {
  const int b = blockIdx.x, tid = threadIdx.x;
  if (b < EDGE_BLKS) {
    int e = b * 256 + tid;
    if (e >= NE) return;
    int s = src[e];
    if (e == 0 || src[e - 1] != s) starts[s] = e;
    if (e == NE - 1 || src[e + 1] != s) ends[s] = e + 1;
    return;
  }
  const int f = b - EDGE_BLKS;  // 0..79
  const int wv = tid >> 6, lq = (tid >> 4) & 3, lc = tid & 15;
  if (f < 64) {
    const float* W = (f < 32) ? W_ih : W_hh;
    short* dst = (f < 32) ? wih_s : whh_s;
    const int ff = f & 31;
    const int g = ff >> 3, db = (ff >> 2) & 1, kt = ff & 3;
    const float s = (g == 2) ? L2E2 : L2E;  // exp2-domain pre-scale
    const float* p = &W[(g * 128 + wv * 32 + db * 16 + lc) * 128 + kt * 32 + lq * 8];
    f32x4 a = *(const f32x4*)p;
    f32x4 c = *(const f32x4*)(p + 4);
    short8 w;
    w[0] = f2bs(a[0] * s); w[1] = f2bs(a[1] * s); w[2] = f2bs(a[2] * s); w[3] = f2bs(a[3] * s);
    w[4] = f2bs(c[0] * s); w[5] = f2bs(c[1] * s); w[6] = f2bs(c[2] * s); w[7] = f2bs(c[3] * s);
    *(short8*)&dst[(ff * 256 + tid) * 8] = w;
  } else {
    const int fo = f - 64;  // 0..15 (W_out: NOT scaled)
    const int db = fo >> 3, kt = fo & 7;
    short8 w;
#pragma unroll
    for (int jj = 0; jj < 8; ++jj)
      w[jj] = f2bs(Wout[(kt * 32 + lq * 8 + jj) * 128 + wv * 32 + db * 16 + lc]);
    *(short8*)&wout_s[(fo * 256 + tid) * 8] = w;
  }
}

// ---- neighbor list build FUSED with the degree histogram ----
__global__ void k_nbr_hist(const int* __restrict__ src, const int* __restrict__ trg,
                           const int* __restrict__ starts, const int* __restrict__ ends,
                           int* __restrict__ nbr, int* __restrict__ ghist) {
  __shared__ int h[MAXD + 1];
  const int tid = threadIdx.x;
  if (tid <= MAXD) h[tid] = 0;
  __syncthreads();
  int e = blockIdx.x * 256 + tid;
  if (e < NE) {
    int s = src[e];
    int pos = e - starts[s];
    if (pos < MAXD) nbr[s * MAXD + pos] = trg[e];
  }
  if (e < NN) {
    int c = ends[e] - starts[e]; c = c > MAXD ? MAXD : c;
    atomicAdd(&h[c], 1);
  }
  __syncthreads();
  if (tid <= MAXD && h[tid] > 0) atomicAdd(&ghist[tid], h[tid]);
}

// ---- scatter with inline descending-bucket scan; gclaim[] zeroed by the
// launch-side memset. Within-bucket order arbitrary. ----
__global__ void k_scat2(const int* __restrict__ starts, const int* __restrict__ ends,
                        const int* __restrict__ ghist, int* __restrict__ gclaim,
                        int* __restrict__ order) {
  __shared__ int lh[MAXD + 1];
  __shared__ int lbase[MAXD + 1];
  __shared__ int sbase[MAXD + 1];
  const int tid = threadIdx.x;
  if (tid <= MAXD) lh[tid] = 0;
  __syncthreads();
  int n = blockIdx.x * 256 + tid;
  int c = 0, rank = 0;
  if (n < NN) {
    c = ends[n] - starts[n]; c = c > MAXD ? MAXD : c;
    rank = atomicAdd(&lh[c], 1);
  }
  if (tid == 0) {
    int tot = 0;
    for (int b = MAXD; b >= 0; --b) { sbase[b] = tot; tot += ghist[b]; }
  }
  __syncthreads();
  if (tid <= MAXD && lh[tid] > 0)
    lbase[tid] = sbase[tid] + atomicAdd(&gclaim[tid], lh[tid]);
  __syncthreads();
  if (n < NN) order[lbase[c] + rank] = n;
}

// ---- proj = X @ W_ih.T + (b_ih+b_hh), bf16 MFMA, permuted layout:
// j = g*128 + wv*32 + db*16 + lc  ->  pos = (wv*16+lc)*8 + g*2 + db.
// r6: conversions via v_cvt_pk_bf16_f32 (epilogue 32 f2bs -> 16 cvt_pk
// per mt; staging 4 f2bs -> 2 cvt_pk). Same RNE rounding. ----
__global__ __launch_bounds__(256)
__attribute__((amdgpu_waves_per_eu(2, 2))) void k_proj(
    const float* __restrict__ x, const short* __restrict__ wih_s,
    const float* __restrict__ b_ih, const float* __restrict__ b_hh,
    short* __restrict__ proj) {
  __shared__ __align__(16) short xs[64 * HPAD];
  const int tid = threadIdx.x;
  const int wv = tid >> 6, lane = tid & 63, lq = lane >> 4, lc = lane & 15;
  const int base = blockIdx.x * 64;

  for (int idx4 = tid; idx4 < 64 * 32; idx4 += 256) {
    int row = idx4 >> 5, k4 = (idx4 & 31) << 2;
    f32x4 v = (f32x4){0.f, 0.f, 0.f, 0.f};
    if (base + row < NN) v = *(const f32x4*)&x[(base + row) * 128 + k4];
    int* xr = (int*)&xs[row * HPAD];
    xr[(k4 >> 1)] = (int)cvtpk(v[0], v[1]);
    xr[(k4 >> 1) + 1] = (int)cvtpk(v[2], v[3]);
  }
  const short8* wihv = (const short8*)wih_s;
  short8 wfrag[4][2][4];
#pragma unroll
  for (int g = 0; g < 4; ++g)
#pragma unroll
    for (int db = 0; db < 2; ++db)
#pragma unroll
      for (int kt = 0; kt < 4; ++kt) {
        short8 w = wihv[(g * 8 + db * 4 + kt) * 256 + tid];
        PIN_AGPR(w);
        wfrag[g][db][kt] = w;
      }
  float bias_v[4][2];
#pragma unroll
  for (int g = 0; g < 4; ++g)
#pragma unroll
    for (int db = 0; db < 2; ++db) {
      int j = g * 128 + wv * 32 + db * 16 + lc;
      bias_v[g][db] = (b_ih[j] + b_hh[j]) * ((g == 2) ? L2E2 : L2E);
    }
  __syncthreads();

#pragma unroll
  for (int mt = 0; mt < 4; ++mt) {
    short8 afrag[4];
#pragma unroll
    for (int kt = 0; kt < 4; ++kt)
      afrag[kt] = *(const short8*)&xs[(mt * 16 + lc) * HPAD + kt * 32 + lq * 8];
    f32x4 acc[4][2];
#pragma unroll
    for (int g = 0; g < 4; ++g)
#pragma unroll
      for (int db = 0; db < 2; ++db) {
        float b = bias_v[g][db];
        acc[g][db] = (f32x4){b, b, b, b};
#pragma unroll
        for (int kt = 0; kt < 4; ++kt)
          acc[g][db] = __builtin_amdgcn_mfma_f32_16x16x32_bf16(
              afrag[kt], wfrag[g][db][kt], acc[g][db], 0, 0, 0);
      }
#pragma unroll
    for (int r = 0; r < 4; ++r) {
      int row = base + mt * 16 + lq * 4 + r;
      if (row < NN) {
        i32x4 w;
        w[0] = (int)cvtpk(acc[0][0][r], acc[0][1][r]);
        w[1] = (int)cvtpk(acc[1][0][r], acc[1][1][r]);
        w[2] = (int)cvtpk(acc[2][0][r], acc[2][1][r]);
        w[3] = (int)cvtpk(acc[3][0][r], acc[3][1][r]);
        *(i32x4*)&proj[row * NG + (wv * 16 + lc) * 8] = w;
      }
    }
  }
}

// ---- LSTM + fused output GEMM. Inner loop unchanged since r5 (W_hh
// AGPR-pinned, exp2-domain gates, distance-1 gl_lds prefetch, one barrier
// per step). NEW (r6): after the T loop, the block computes
// out[rows] = [x|h] @ W_out for its 32 nodes directly:
//  - [x|h] staged into the dead pbuf (32 x 272 shorts = 17.4 KB <= 32 KB),
//  - W_out frags loaded into the DEAD wfrag AGPR space (PIN_AGPR) so the
//    arch-VGPR file stays flat (spill watchdog: WRITE_SIZE ~= out bytes),
//  - 32 MFMA + scattered f32 stores. Kills the separate k_out kernel and
//    the agg round-trip (15 MB). ----
__global__ __launch_bounds__(256)
__attribute__((amdgpu_waves_per_eu(2, 2))) void k_lstm(
    const short* __restrict__ whh_s, const short* __restrict__ proj,
    const int* __restrict__ order, const int* __restrict__ starts,
    const int* __restrict__ ends, const int* __restrict__ nbr,
    const short* __restrict__ wout_s, const float* __restrict__ x,
    float* __restrict__ out) {
  __shared__ __align__(16) short h_s[2][BATCH * HPAD];   // 18432 B
  __shared__ __align__(16) short pbuf[4][8][64 * 8];     // 32768 B, wave-private slots
  __shared__ unsigned short nbr_s[BATCH][MAXD];          // 3072 B
  __shared__ int nodes_s[BATCH];
  __shared__ int cnts_s[BATCH];

  const int tid = threadIdx.x;
  const int wv = tid >> 6, lane = tid & 63, lq = lane >> 4, lc = lane & 15;

  const short8* whhv = (const short8*)whh_s;
  short8 wfrag[4][2][4];
#pragma unroll
  for (int g = 0; g < 4; ++g)
#pragma unroll
    for (int db = 0; db < 2; ++db)
#pragma unroll
      for (int kt = 0; kt < 4; ++kt) {
        short8 w = whhv[(g * 8 + db * 4 + kt) * 256 + tid];
        PIN_AGPR(w);
        wfrag[g][db][kt] = w;
      }

  const int batch = blockIdx.x;
  if (tid < BATCH) {
    int gidx = batch * BATCH + tid;
    int node = 0, c = 0;
    if (gidx < NN) {
      node = order[gidx];
      c = ends[node] - starts[node]; c = c > MAXD ? MAXD : c;
    }
    nodes_s[tid] = node;
    cnts_s[tid] = c;
  }
  __syncthreads();
  for (int idx = tid; idx < BATCH * HPAD / 2; idx += 256)
    ((int*)h_s[0])[idx] = 0;
  for (int idx = tid; idx < BATCH * MAXD; idx += 256) {
    int m = idx / MAXD, p = idx - m * MAXD;
    nbr_s[m][p] = (unsigned short)nbr[nodes_s[m] * MAXD + p];
  }
  __syncthreads();
  const int T = cnts_s[0];  // descending-bucket grouping -> batch max

  // counts packed 4-per-int (each <= 48 fits in 8 bits)
  int cp[2];
#pragma unroll
  for (int mt = 0; mt < 2; ++mt) {
    int p = 0;
#pragma unroll
    for (int r = 0; r < 4; ++r) p |= cnts_s[mt * 16 + lq * 4 + r] << (r * 8);
    cp[mt] = p;
  }

  float c_v[2][2][4];
  s16x4 hvp[2][2];  // last-written h (bf16) for copy-forward of frozen rows
#pragma unroll
  for (int mt = 0; mt < 2; ++mt)
#pragma unroll
    for (int db = 0; db < 2; ++db) {
#pragma unroll
      for (int r = 0; r < 4; ++r) c_v[mt][db][r] = 0.0f;
      hvp[mt][db] = (s16x4){0, 0, 0, 0};
    }

  const int pcol = (wv * 16 + lc) * 8;
  if (T > 0) {  // prologue: async-gather t=0 slices into pbuf
#pragma unroll
    for (int mt = 0; mt < 2; ++mt)
#pragma unroll
      for (int r = 0; r < 4; ++r) {
        int m = mt * 16 + lq * 4 + r;
        int nb_i = (0 < ((cp[mt] >> (r * 8)) & 255)) ? (int)nbr_s[m][0] : 0;
        gl_lds16(&proj[nb_i * NG + pcol], &pbuf[wv][mt * 4 + r][0]);
      }
  }

  for (int t = 0; t < T; ++t) {
    __syncthreads();  // drains prefetch (vmcnt) + makes h writes visible
    const short* hb = h_s[t & 1];
    short* hw = h_s[(t + 1) & 1];
    const int tn = t + 1;
    const int ts = tn < MAXD ? tn : 0;
#pragma unroll
    for (int mt = 0; mt < 2; ++mt) {
      // consume this step's gathered slices (wave-private slots)
      i32x4 pvi[4];
#pragma unroll
      for (int r = 0; r < 4; ++r)
        pvi[r] = *(const i32x4*)&pbuf[wv][mt * 4 + r][lane * 8];
      f32x4 acc[4][2];
#pragma unroll
      for (int g = 0; g < 4; ++g)
#pragma unroll
        for (int r = 0; r < 4; ++r) {
          unsigned u = (unsigned)pvi[r][g];  // two bf16: db0=lo, db1=hi
          acc[g][0][r] = __builtin_bit_cast(float, u << 16);
          acc[g][1][r] = __builtin_bit_cast(float, u & 0xffff0000u);
        }
      __builtin_amdgcn_sched_barrier(0);  // pvi fully consumed before overwrite
      if (tn < T) {  // prefetch t+1 into the same (now free) slots
#pragma unroll
        for (int r = 0; r < 4; ++r) {
          int m = mt * 16 + lq * 4 + r;
          int nb_i = (tn < ((cp[mt] >> (r * 8)) & 255)) ? (int)nbr_s[m][ts] : 0;
          gl_lds16(&proj[nb_i * NG + pcol], &pbuf[wv][mt * 4 + r][0]);
        }
      }
      __builtin_amdgcn_sched_barrier(0);  // keep prefetch issue early
      short8 afrag[4];
#pragma unroll
      for (int kt = 0; kt < 4; ++kt)
        afrag[kt] = *(const short8*)&hb[(mt * 16 + lc) * HPAD + kt * 32 + lq * 8];
#pragma unroll
      for (int g = 0; g < 4; ++g)
#pragma unroll
        for (int db = 0; db < 2; ++db)
#pragma unroll
          for (int kt = 0; kt < 4; ++kt)
            acc[g][db] = __builtin_amdgcn_mfma_f32_16x16x32_bf16(
                afrag[kt], wfrag[g][db][kt], acc[g][db], 0, 0, 0);
#pragma unroll
      for (int db = 0; db < 2; ++db)
#pragma unroll
        for (int r = 0; r < 4; ++r) {
          float Ei = __builtin_amdgcn_exp2f(-acc[0][db][r]);
          float Eg = __builtin_amdgcn_exp2f(fminf(acc[2][db][r], 125.f));
          float ig = (Eg - 1.f) *
                     __builtin_amdgcn_rcpf((1.f + Ei) * (1.f + Eg));
          float fv = __builtin_amdgcn_rcpf(
              1.f + __builtin_amdgcn_exp2f(-acc[1][db][r]));
          float c2 = fv * c_v[mt][db][r] + ig;
          float Eo = __builtin_amdgcn_exp2f(-acc[3][db][r]);
          float Ec = __builtin_amdgcn_exp2f(fminf(c2 * L2E2, 125.f));
          float h2 = (Ec - 1.f) *
                     __builtin_amdgcn_rcpf((1.f + Eo) * (1.f + Ec));
          if (t < ((cp[mt] >> (r * 8)) & 255)) {
            c_v[mt][db][r] = c2;
            hvp[mt][db][r] = f2bs(h2);
          }
        }
      // unconditional write of (new or carried) h into the other buffer
#pragma unroll
      for (int db = 0; db < 2; ++db)
#pragma unroll
        for (int r = 0; r < 4; ++r)
          hw[(mt * 16 + lq * 4 + r) * HPAD + wv * 32 + db * 16 + lc] =
              hvp[mt][db][r];
    }
  }
  __syncthreads();  // last step's h writes visible; pbuf prefetches drained

  // ---- fused output GEMM: out[32 rows] = [x|h] @ W_out ----
  const short* hf = h_s[T & 1];
  short* xt = (short*)pbuf;  // 32 x XTS(272) shorts = 17408 B, reuses pbuf
  // h half: copy 32x128 bf16 as ints (HPAD-strided -> XTS-strided)
  for (int idx = tid; idx < BATCH * 64; idx += 256) {
    int m = idx >> 6, d2 = idx & 63;
    ((int*)xt)[m * (XTS / 2) + 64 + d2] = ((const int*)&hf[m * HPAD])[d2];
  }
  // x half: gather rows by node id, convert f32->bf16 (cvt_pk)
  for (int idx4 = tid; idx4 < BATCH * 32; idx4 += 256) {
    int m = idx4 >> 5, k4 = (idx4 & 31) << 2;
    f32x4 v = *(const f32x4*)&x[nodes_s[m] * 128 + k4];
    int* xr = (int*)xt + m * (XTS / 2);
    xr[(k4 >> 1)] = (int)cvtpk(v[0], v[1]);
    xr[(k4 >> 1) + 1] = (int)cvtpk(v[2], v[3]);
  }
  // W_out frags into the dead wfrag AGPR space
  const short8* wov = (const short8*)wout_s;
  short8 wf[2][8];
#pragma unroll
  for (int db = 0; db < 2; ++db)
#pragma unroll
    for (int kt = 0; kt < 8; ++kt) {
      short8 w = wov[(db * 8 + kt) * 256 + tid];
      PIN_AGPR(w);
      wf[db][kt] = w;
    }
  __syncthreads();  // xt ready
#pragma unroll
  for (int mt = 0; mt < 2; ++mt) {
    short8 afrag[8];
#pragma unroll
    for (int kt = 0; kt < 8; ++kt)
      afrag[kt] = *(const short8*)&xt[(mt * 16 + lc) * XTS + kt * 32 + lq * 8];
    f32x4 acc[2];
#pragma unroll
    for (int db = 0; db < 2; ++db) {
      acc[db] = (f32x4){0.f, 0.f, 0.f, 0.f};
#pragma unroll
      for (int kt = 0; kt < 8; ++kt)
        acc[db] = __builtin_amdgcn_mfma_f32_16x16x32_bf16(
            afrag[kt], wf[db][kt], acc[db], 0, 0, 0);
    }
#pragma unroll
    for (int db = 0; db < 2; ++db)
#pragma unroll
      for (int r = 0; r < 4; ++r) {
        int m = mt * 16 + lq * 4 + r;
        if (batch * BATCH + m < NN)
          out[nodes_s[m] * 128 + wv * 32 + db * 16 + lc] = acc[db][r];
      }
  }
}

extern "C" void kernel_launch(void* const* d_in, const int* in_sizes, int n_in,
                              void* d_out, int out_size, void* d_ws,
                              size_t ws_size, hipStream_t stream) {
  (void)in_sizes; (void)n_in; (void)out_size; (void)ws_size;
  const float* x     = (const float*)d_in[0];
  const float* W_ih  = (const float*)d_in[1];
  const float* W_hh  = (const float*)d_in[2];
  const float* b_ih  = (const float*)d_in[3];
  const float* b_hh  = (const float*)d_in[4];
  const float* W_out = (const float*)d_in[5];
  const int*   esrc  = (const int*)d_in[6];
  const int*   etrg  = (const int*)d_in[7];
  float* out = (float*)d_out;
  char* ws = (char*)d_ws;

  int*   starts = (int*)(ws + 0);          // 120,000 B
  int*   ends   = (int*)(ws + 120064);     // 120,000 B
  int*   ghist  = (int*)(ws + 240128);     // 196 B (zeroed by memset)
  int*   gclaim = (int*)(ws + 240384);     // 196 B (zeroed by memset)
  int*   order  = (int*)(ws + 240640);     // 120,000 B
  int*   nbr    = (int*)(ws + 360704);     // 5,760,000 B
  short* proj   = (short*)(ws + 6120704);  // 30,720,000 B (bf16, scaled, permuted)
  short* wih_s  = (short*)(ws + 36840704); // 131,072 B (bf16, frag-swizzled, scaled)
  short* whh_s  = (short*)(ws + 36971776); // 131,072 B
  short* wout_s = (short*)(ws + 37102848); // 65,536 B

  (void)hipMemsetAsync(d_ws, 0, 240640, stream);  // starts+ends+ghist+gclaim

  k_edges_wcvt<<<EDGE_BLKS + 80, 256, 0, stream>>>(esrc, starts, ends, W_ih,
                                                   W_hh, W_out, wih_s, whh_s,
                                                   wout_s);
  k_nbr_hist<<<1875, 256, 0, stream>>>(esrc, etrg, starts, ends, nbr, ghist);
  k_scat2<<<118, 256, 0, stream>>>(starts, ends, ghist, gclaim, order);
  k_proj <<<NGB, 256, 0, stream>>>(x, wih_s, b_ih, b_hh, proj);
  k_lstm <<<NB, 256, 0, stream>>>(whh_s, proj, order, starts, ends, nbr,
                                  wout_s, x, out);
}